// Round 10
// baseline (223.921 us; speedup 1.0000x reference)
//
#include <hip/hip_runtime.h>
#include <hip/hip_bf16.h>
#include <stdint.h>

#define NFEATS 128
#define BKT_CAP 1536   // max edges per 128-node src bucket (mean 768, sigma ~28)

typedef __attribute__((ext_vector_type(8))) short bf16x8;
typedef __attribute__((ext_vector_type(4))) float f32x4;
typedef __attribute__((ext_vector_type(4))) short short4v;

__device__ inline short f2bf(float f) {
    union { float f; unsigned u; } c; c.f = f;
    unsigned u = c.u;
    return (short)((u + 0x7FFFu + ((u >> 16) & 1u)) >> 16);  // RNE
}
__device__ inline float bf2f(short v) {
    union { unsigned u; float f; } c;
    c.u = ((unsigned)(unsigned short)v) << 16;
    return c.f;
}

// ---------- kernel 0: zero bucket cursors ----------
__global__ void zero_kernel(int* __restrict__ cur, int nbkt) {
    int i = blockIdx.x * blockDim.x + threadIdx.x;
    if (i < nbkt) cur[i] = 0;
}

// ---------- kernel 1: scatter edges into src-buckets ----------
// Packs {dst, e | srcloc<<20}. Requires n_edges < 2^20 (here 600000).
__global__ __launch_bounds__(256) void scatter_kernel(
    const int* __restrict__ src, const int* __restrict__ dst,
    int* __restrict__ cur, int2* __restrict__ ed, int n_edges)
{
    int stride = gridDim.x * 256;
    for (int e = blockIdx.x * 256 + threadIdx.x; e < n_edges; e += stride) {
        int s = src[e];
        int b = s >> 7;
        int pos = atomicAdd(&cur[b], 1);
        if (pos < BKT_CAP) {
            int2 v;
            v.x = dst[e];
            v.y = e | ((s & 127) << 20);
            ed[(size_t)b * BKT_CAP + pos] = v;
        }
    }
}

// ---------- kernel 2: precompute B = user @ W1[:,128:].T  (R5-proven body) ----------
__global__ __launch_bounds__(512, 4) void precompute_B_kernel(
    const float* __restrict__ user, const float* __restrict__ W1,
    short* __restrict__ B, int n_nodes)
{
    __shared__ __align__(1024) uint8_t lds[34816 + 32768];  // [W/buf0 | buf1]

    const float* __restrict__ X = user;
    const int k_off4 = 32;   // cols 128..255 in float4 units

    const int tid = threadIdx.x;
    const int w = tid >> 6, lane = tid & 63;
    const int r16 = lane & 15, q = lane >> 4;
    const int rowgrp = w >> 1, colhalf = w & 1;

    // stage W (fp32 -> bf16) into padded LDS
    {
        short (*Wl)[136] = (short (*)[136])lds;
        const float4* W4 = (const float4*)W1;   // row stride 64 float4
        for (int i = tid; i < 128 * 32; i += 512) {
            int j = i >> 5, c = i & 31;
            float4 wv = W4[j * 64 + k_off4 + c];
            short4v p;
            p[0] = f2bf(wv.x); p[1] = f2bf(wv.y); p[2] = f2bf(wv.z); p[3] = f2bf(wv.w);
            *(short4v*)&Wl[j][c * 4] = p;
        }
    }
    __syncthreads();

    bf16x8 wfrag[4][4];
    {
        short (*Wl)[136] = (short (*)[136])lds;
#pragma unroll
        for (int n = 0; n < 4; ++n) {
            int col = colhalf * 64 + n * 16 + r16;
#pragma unroll
            for (int kk = 0; kk < 4; ++kk)
                wfrag[n][kk] = *(const bf16x8*)&Wl[col][kk * 32 + q * 8];
        }
    }
    __syncthreads();   // W region reusable as X buffer 0

    const int n_tiles = (n_nodes + 63) >> 6;

    auto stage = [&](int buf, int t) {
        uint8_t* base = lds + buf * 34816;
#pragma unroll
        for (int i = 0; i < 4; ++i) {
            int o = (w << 12) + (i << 10) + (lane << 4);
            int r = o >> 9;
            int c_lds = (o >> 4) & 31;
            int node = (t << 6) + r;
            if (node >= n_nodes) node = n_nodes - 1;
            const uint8_t* gp = (const uint8_t*)X + (size_t)node * 512
                              + (size_t)(((c_lds ^ (r & 7)) << 4));
            auto g1 = (const __attribute__((address_space(1))) uint32_t*)gp;
            auto l3 = (__attribute__((address_space(3))) uint32_t*)(base + (w << 12) + (i << 10));
            __builtin_amdgcn_global_load_lds(g1, l3, 16, 0, 0);
        }
    };

    int t = blockIdx.x;
    if (t < n_tiles) stage(0, t);
    int cur = 0;

    for (; t < n_tiles; t += gridDim.x) {
        __syncthreads();
        int tn = t + gridDim.x;
        if (tn < n_tiles) stage(cur ^ 1, tn);

        const uint8_t* base = lds + cur * 34816;
        const int r = rowgrp * 16 + r16;
        const uint8_t* rowp = base + r * 512;
        const int s = r & 7;
        bf16x8 afrag[4];
#pragma unroll
        for (int kk = 0; kk < 4; ++kk) {
            int c0 = kk * 8 + q * 2;
            float4 v0 = *(const float4*)(rowp + ((c0 ^ s) << 4));
            float4 v1 = *(const float4*)(rowp + (((c0 + 1) ^ s) << 4));
            bf16x8 f;
            f[0] = f2bf(v0.x); f[1] = f2bf(v0.y); f[2] = f2bf(v0.z); f[3] = f2bf(v0.w);
            f[4] = f2bf(v1.x); f[5] = f2bf(v1.y); f[6] = f2bf(v1.z); f[7] = f2bf(v1.w);
            afrag[kk] = f;
        }

        f32x4 acc[4];
#pragma unroll
        for (int n = 0; n < 4; ++n) {
            f32x4 z = {0.f, 0.f, 0.f, 0.f};
            acc[n] = z;
        }
#pragma unroll
        for (int n = 0; n < 4; ++n)
#pragma unroll
            for (int kk = 0; kk < 4; ++kk)
                acc[n] = __builtin_amdgcn_mfma_f32_16x16x32_bf16(afrag[kk], wfrag[n][kk], acc[n], 0, 0, 0);

        const int row0 = (t << 6) + rowgrp * 16 + q * 4;
#pragma unroll
        for (int rr = 0; rr < 4; ++rr) {
            int row = row0 + rr;
            if (row < n_nodes) {
                short* orow = B + (size_t)row * NFEATS;
#pragma unroll
                for (int n = 0; n < 4; ++n)
                    orow[colhalf * 64 + n * 16 + r16] = f2bf(acc[n][rr]);
            }
        }
        cur ^= 1;
    }
}

// ---------- kernel 3: fused A-tile (in LDS, never written to global) + edges ----------
// Each block owns 2 src-buckets of 128 nodes. Per bucket:
//   A-phase: A[128][128] = item_rows @ W1a.T + b1 via MFMA -> LDS (bf16)
//   edge-phase: for bucket edges, gather B[dst], read A[srcloc] from LDS,
//               score = relu(a+b).w2 + b2 -> out[e]
__global__ __launch_bounds__(512) void fused_kernel(
    const float* __restrict__ item, const float* __restrict__ W1,
    const float* __restrict__ b1, const float* __restrict__ W2,
    const float* __restrict__ b2, const short* __restrict__ B,
    const int2* __restrict__ ed, const int* __restrict__ cnt_arr,
    float* __restrict__ out, int n_nodes, int nbkt)
{
    __shared__ short Wlds[128][136];
    __shared__ short Alds[128][136];

    const int tid = threadIdx.x;
    const int w = tid >> 6, lane = tid & 63;
    const int r16 = lane & 15, q = lane >> 4;   // within-wave
    const int qw = tid >> 4;                    // 32 quarter-waves per block

    // stage W1a (cols 0..127) fp32->bf16 into padded LDS
    {
        const float4* W4 = (const float4*)W1;   // row stride 64 float4
        for (int i = tid; i < 128 * 32; i += 512) {
            int j = i >> 5, c = i & 31;
            float4 wv = W4[j * 64 + c];
            short4v p;
            p[0] = f2bf(wv.x); p[1] = f2bf(wv.y); p[2] = f2bf(wv.z); p[3] = f2bf(wv.w);
            *(short4v*)&Wlds[j][c * 4] = p;
        }
    }

    float w2v[8];
#pragma unroll
    for (int j = 0; j < 8; ++j) w2v[j] = W2[r16 * 8 + j];
    const float b2v = b2[0];

    __syncthreads();

    const int b0 = blockIdx.x * 2;
    for (int bkt = b0; bkt < b0 + 2 && bkt < nbkt; ++bkt) {
        // ---- A-phase: wave w computes rows w*16 .. w*16+15 of this tile ----
        int row = bkt * 128 + w * 16 + r16;
        int rowc = row < n_nodes ? row : n_nodes - 1;
        const float* xr = item + (size_t)rowc * NFEATS;
        bf16x8 afrag[4];
#pragma unroll
        for (int kk = 0; kk < 4; ++kk) {
            int k0 = kk * 32 + q * 8;
            float4 lo = *(const float4*)(xr + k0);
            float4 hi = *(const float4*)(xr + k0 + 4);
            bf16x8 f;
            f[0] = f2bf(lo.x); f[1] = f2bf(lo.y); f[2] = f2bf(lo.z); f[3] = f2bf(lo.w);
            f[4] = f2bf(hi.x); f[5] = f2bf(hi.y); f[6] = f2bf(hi.z); f[7] = f2bf(hi.w);
            afrag[kk] = f;
        }

        f32x4 acc[8];
#pragma unroll
        for (int n = 0; n < 8; ++n) {
            float bv = b1[n * 16 + r16];
            f32x4 init = {bv, bv, bv, bv};
            acc[n] = init;
        }
#pragma unroll
        for (int n = 0; n < 8; ++n)
#pragma unroll
            for (int kk = 0; kk < 4; ++kk) {
                bf16x8 wf = *(const bf16x8*)&Wlds[n * 16 + r16][kk * 32 + q * 8];
                acc[n] = __builtin_amdgcn_mfma_f32_16x16x32_bf16(afrag[kk], wf, acc[n], 0, 0, 0);
            }

        __syncthreads();   // prev bucket's edge-phase done reading Alds

        // C/D layout: col = lane&15, row = (lane>>4)*4 + rr
#pragma unroll
        for (int rr = 0; rr < 4; ++rr)
#pragma unroll
            for (int n = 0; n < 8; ++n)
                Alds[w * 16 + q * 4 + rr][n * 16 + r16] = f2bf(acc[n][rr]);

        __syncthreads();   // A-tile ready

        // ---- edge phase: one quarter-wave per edge, 2 in flight ----
        const int cnt = min(cnt_arr[bkt], BKT_CAP);
        const int2* eb = ed + (size_t)bkt * BKT_CAP;
        for (int p0 = qw; p0 < cnt; p0 += 64) {
            int p1 = p0 + 32;
            bool has1 = p1 < cnt;
            int2 pe0 = eb[p0];
            int2 pe1 = has1 ? eb[p1] : pe0;
            int sl0 = (pe0.y >> 20) & 127, e0 = pe0.y & 0xFFFFF;
            int sl1 = (pe1.y >> 20) & 127, e1 = pe1.y & 0xFFFFF;

            bf16x8 bv0 = *(const bf16x8*)(B + (size_t)pe0.x * NFEATS + r16 * 8);
            bf16x8 bv1 = *(const bf16x8*)(B + (size_t)pe1.x * NFEATS + r16 * 8);
            bf16x8 av0 = *(const bf16x8*)&Alds[sl0][r16 * 8];
            bf16x8 av1 = *(const bf16x8*)&Alds[sl1][r16 * 8];

            float s0 = 0.f, s1 = 0.f;
#pragma unroll
            for (int j = 0; j < 8; ++j) {
                float h0 = bf2f(av0[j]) + bf2f(bv0[j]);
                h0 = fmaxf(h0, 0.f);
                s0 = fmaf(h0, w2v[j], s0);
                float h1 = bf2f(av1[j]) + bf2f(bv1[j]);
                h1 = fmaxf(h1, 0.f);
                s1 = fmaf(h1, w2v[j], s1);
            }
#pragma unroll
            for (int sh = 1; sh <= 8; sh <<= 1) {
                s0 += __shfl_xor(s0, sh);
                s1 += __shfl_xor(s1, sh);
            }
            if (r16 == 0) {
                out[e0] = s0 + b2v;
                if (has1) out[e1] = s1 + b2v;
            }
        }
    }
}

extern "C" void kernel_launch(void* const* d_in, const int* in_sizes, int n_in,
                              void* d_out, int out_size, void* d_ws, size_t ws_size,
                              hipStream_t stream) {
    const float* item = (const float*)d_in[0];
    const float* user = (const float*)d_in[1];
    const float* W1   = (const float*)d_in[2];
    const float* b1   = (const float*)d_in[3];
    const float* W2   = (const float*)d_in[4];
    const float* b2   = (const float*)d_in[5];
    const int*   src  = (const int*)d_in[6];
    const int*   dst  = (const int*)d_in[7];
    float* out = (float*)d_out;

    const int n_nodes = in_sizes[0] / NFEATS;
    const int n_edges = in_sizes[6];
    const int nbkt = (n_nodes + 127) >> 7;

    // workspace layout
    short* B = (short*)d_ws;                                  // [n_nodes][128] bf16
    size_t off = (size_t)n_nodes * NFEATS * 2;
    off = (off + 255) & ~(size_t)255;
    int* cur = (int*)((uint8_t*)d_ws + off);                  // [nbkt]
    off += ((size_t)nbkt * 4 + 255) & ~(size_t)255;
    int2* ed = (int2*)((uint8_t*)d_ws + off);                 // [nbkt][BKT_CAP]

    zero_kernel<<<(nbkt + 1023) / 1024, 1024, 0, stream>>>(cur, nbkt);
    scatter_kernel<<<256, 256, 0, stream>>>(src, dst, cur, ed, n_edges);
    precompute_B_kernel<<<256, 512, 0, stream>>>(user, W1, B, n_nodes);
    fused_kernel<<<(nbkt + 1) / 2, 512, 0, stream>>>(
        item, W1, b1, W2, b2, B, ed, cur, out, n_nodes, nbkt);
}

// Round 11
// 86.721 us; speedup vs baseline: 2.5821x; 2.5821x over previous
//
#include <hip/hip_runtime.h>
#include <hip/hip_bf16.h>
#include <stdint.h>

#define NFEATS 128
#define BKT_CAP 1536   // max edges per 128-node src bucket (mean 768; fixed inputs)
#define NBKT_MAX 800

typedef __attribute__((ext_vector_type(8))) short bf16x8;
typedef __attribute__((ext_vector_type(4))) float f32x4;
typedef __attribute__((ext_vector_type(4))) short short4v;

__device__ inline short f2bf(float f) {
    union { float f; unsigned u; } c; c.f = f;
    unsigned u = c.u;
    return (short)((u + 0x7FFFu + ((u >> 16) & 1u)) >> 16);  // RNE
}
__device__ inline float bf2f(short v) {
    union { unsigned u; float f; } c;
    c.u = ((unsigned)(unsigned short)v) << 16;
    return c.f;
}

// ---------- kernel 0: zero bucket cursors ----------
__global__ void zero_kernel(int* __restrict__ cur, int nbkt) {
    int i = blockIdx.x * blockDim.x + threadIdx.x;
    if (i < nbkt) cur[i] = 0;
}

// ---------- kernel 1: scatter via per-block LDS histogram + range reservation ----
// Each block owns a contiguous edge chunk. LDS atomics for counting, ONE global
// atomicAdd per (block, non-empty bucket) to reserve a contiguous range, then
// contiguous writes into the reserved runs (write-merge friendly).
__global__ __launch_bounds__(1024) void scatter_kernel(
    const int* __restrict__ src, const int* __restrict__ dst,
    int* __restrict__ cur, int2* __restrict__ ed, int n_edges, int nbkt)
{
    __shared__ int hist[NBKT_MAX];
    __shared__ int base[NBKT_MAX];
    const int tid = threadIdx.x;
    const int chunk = (n_edges + gridDim.x - 1) / gridDim.x;
    const int e0 = blockIdx.x * chunk;
    const int e1 = min(e0 + chunk, n_edges);

    for (int i = tid; i < nbkt; i += 1024) hist[i] = 0;
    __syncthreads();

    for (int e = e0 + tid; e < e1; e += 1024)
        atomicAdd(&hist[src[e] >> 7], 1);
    __syncthreads();

    for (int i = tid; i < nbkt; i += 1024) {
        int c = hist[i];
        base[i] = c ? atomicAdd(&cur[i], c) : 0;
        hist[i] = 0;
    }
    __syncthreads();

    for (int e = e0 + tid; e < e1; e += 1024) {
        int s = src[e];
        int b = s >> 7;
        int pos = base[b] + atomicAdd(&hist[b], 1);
        if (pos < BKT_CAP) {
            int2 v;
            v.x = dst[e];
            v.y = e | ((s & 127) << 20);   // n_edges < 2^20
            ed[(size_t)b * BKT_CAP + pos] = v;
        }
    }
}

// ---------- kernel 2: precompute B = user @ W1[:,128:].T  (R5-proven body) ----------
__global__ __launch_bounds__(512, 4) void precompute_B_kernel(
    const float* __restrict__ user, const float* __restrict__ W1,
    short* __restrict__ B, int n_nodes)
{
    __shared__ __align__(1024) uint8_t lds[34816 + 32768];  // [W/buf0 | buf1]

    const float* __restrict__ X = user;
    const int k_off4 = 32;   // cols 128..255 in float4 units

    const int tid = threadIdx.x;
    const int w = tid >> 6, lane = tid & 63;
    const int r16 = lane & 15, q = lane >> 4;
    const int rowgrp = w >> 1, colhalf = w & 1;

    {
        short (*Wl)[136] = (short (*)[136])lds;
        const float4* W4 = (const float4*)W1;   // row stride 64 float4
        for (int i = tid; i < 128 * 32; i += 512) {
            int j = i >> 5, c = i & 31;
            float4 wv = W4[j * 64 + k_off4 + c];
            short4v p;
            p[0] = f2bf(wv.x); p[1] = f2bf(wv.y); p[2] = f2bf(wv.z); p[3] = f2bf(wv.w);
            *(short4v*)&Wl[j][c * 4] = p;
        }
    }
    __syncthreads();

    bf16x8 wfrag[4][4];
    {
        short (*Wl)[136] = (short (*)[136])lds;
#pragma unroll
        for (int n = 0; n < 4; ++n) {
            int col = colhalf * 64 + n * 16 + r16;
#pragma unroll
            for (int kk = 0; kk < 4; ++kk)
                wfrag[n][kk] = *(const bf16x8*)&Wl[col][kk * 32 + q * 8];
        }
    }
    __syncthreads();   // W region reusable as X buffer 0

    const int n_tiles = (n_nodes + 63) >> 6;

    auto stage = [&](int buf, int t) {
        uint8_t* base = lds + buf * 34816;
#pragma unroll
        for (int i = 0; i < 4; ++i) {
            int o = (w << 12) + (i << 10) + (lane << 4);
            int r = o >> 9;
            int c_lds = (o >> 4) & 31;
            int node = (t << 6) + r;
            if (node >= n_nodes) node = n_nodes - 1;
            const uint8_t* gp = (const uint8_t*)X + (size_t)node * 512
                              + (size_t)(((c_lds ^ (r & 7)) << 4));
            auto g1 = (const __attribute__((address_space(1))) uint32_t*)gp;
            auto l3 = (__attribute__((address_space(3))) uint32_t*)(base + (w << 12) + (i << 10));
            __builtin_amdgcn_global_load_lds(g1, l3, 16, 0, 0);
        }
    };

    int t = blockIdx.x;
    if (t < n_tiles) stage(0, t);
    int cur = 0;

    for (; t < n_tiles; t += gridDim.x) {
        __syncthreads();
        int tn = t + gridDim.x;
        if (tn < n_tiles) stage(cur ^ 1, tn);

        const uint8_t* base = lds + cur * 34816;
        const int r = rowgrp * 16 + r16;
        const uint8_t* rowp = base + r * 512;
        const int s = r & 7;
        bf16x8 afrag[4];
#pragma unroll
        for (int kk = 0; kk < 4; ++kk) {
            int c0 = kk * 8 + q * 2;
            float4 v0 = *(const float4*)(rowp + ((c0 ^ s) << 4));
            float4 v1 = *(const float4*)(rowp + (((c0 + 1) ^ s) << 4));
            bf16x8 f;
            f[0] = f2bf(v0.x); f[1] = f2bf(v0.y); f[2] = f2bf(v0.z); f[3] = f2bf(v0.w);
            f[4] = f2bf(v1.x); f[5] = f2bf(v1.y); f[6] = f2bf(v1.z); f[7] = f2bf(v1.w);
            afrag[kk] = f;
        }

        f32x4 acc[4];
#pragma unroll
        for (int n = 0; n < 4; ++n) {
            f32x4 z = {0.f, 0.f, 0.f, 0.f};
            acc[n] = z;
        }
#pragma unroll
        for (int n = 0; n < 4; ++n)
#pragma unroll
            for (int kk = 0; kk < 4; ++kk)
                acc[n] = __builtin_amdgcn_mfma_f32_16x16x32_bf16(afrag[kk], wfrag[n][kk], acc[n], 0, 0, 0);

        const int row0 = (t << 6) + rowgrp * 16 + q * 4;
#pragma unroll
        for (int rr = 0; rr < 4; ++rr) {
            int row = row0 + rr;
            if (row < n_nodes) {
                short* orow = B + (size_t)row * NFEATS;
#pragma unroll
                for (int n = 0; n < 4; ++n)
                    orow[colhalf * 64 + n * 16 + r16] = f2bf(acc[n][rr]);
            }
        }
        cur ^= 1;
    }
}

// ---------- kernel 3: fused A-tile-in-LDS + edge scoring, 1 bucket per block ----
// Single 34.8KB LDS buffer: holds W1a during the A-phase, then is OVERWRITTEN
// with the A-tile (W is dead after the MFMAs) -> 4 blocks/CU, 32 waves/CU in
// the edge phase. Edge phase: quarter-wave per edge, 4 in flight.
__global__ __launch_bounds__(512, 4) void fused_kernel(
    const float* __restrict__ item, const float* __restrict__ W1,
    const float* __restrict__ b1, const float* __restrict__ W2,
    const float* __restrict__ b2, const short* __restrict__ B,
    const int2* __restrict__ ed, const int* __restrict__ cnt_arr,
    float* __restrict__ out, int n_nodes, int nbkt)
{
    __shared__ short WA[128][136];   // W1a, then A-tile

    const int tid = threadIdx.x;
    const int w = tid >> 6, lane = tid & 63;
    const int r16 = lane & 15, q = lane >> 4;
    const int qw = tid >> 4;                    // 32 quarter-waves per block

    // stage W1a (cols 0..127) fp32->bf16
    {
        const float4* W4 = (const float4*)W1;   // row stride 64 float4
        for (int i = tid; i < 128 * 32; i += 512) {
            int j = i >> 5, c = i & 31;
            float4 wv = W4[j * 64 + c];
            short4v p;
            p[0] = f2bf(wv.x); p[1] = f2bf(wv.y); p[2] = f2bf(wv.z); p[3] = f2bf(wv.w);
            *(short4v*)&WA[j][c * 4] = p;
        }
    }

    float w2v[8];
#pragma unroll
    for (int j = 0; j < 8; ++j) w2v[j] = W2[r16 * 8 + j];
    const float b2v = b2[0];

    const int bkt = blockIdx.x;

    // A-phase inputs (independent of LDS): item rows, bias
    int row = bkt * 128 + w * 16 + r16;
    int rowc = row < n_nodes ? row : n_nodes - 1;
    const float* xr = item + (size_t)rowc * NFEATS;
    bf16x8 afrag[4];
#pragma unroll
    for (int kk = 0; kk < 4; ++kk) {
        int k0 = kk * 32 + q * 8;
        float4 lo = *(const float4*)(xr + k0);
        float4 hi = *(const float4*)(xr + k0 + 4);
        bf16x8 f;
        f[0] = f2bf(lo.x); f[1] = f2bf(lo.y); f[2] = f2bf(lo.z); f[3] = f2bf(lo.w);
        f[4] = f2bf(hi.x); f[5] = f2bf(hi.y); f[6] = f2bf(hi.z); f[7] = f2bf(hi.w);
        afrag[kk] = f;
    }

    f32x4 acc[8];
#pragma unroll
    for (int n = 0; n < 8; ++n) {
        float bv = b1[n * 16 + r16];
        f32x4 init = {bv, bv, bv, bv};
        acc[n] = init;
    }

    __syncthreads();   // W staged

#pragma unroll
    for (int n = 0; n < 8; ++n)
#pragma unroll
        for (int kk = 0; kk < 4; ++kk) {
            bf16x8 wf = *(const bf16x8*)&WA[n * 16 + r16][kk * 32 + q * 8];
            acc[n] = __builtin_amdgcn_mfma_f32_16x16x32_bf16(afrag[kk], wf, acc[n], 0, 0, 0);
        }

    __syncthreads();   // all W reads done -> safe to overwrite with A

    // C/D layout: col = lane&15, row = (lane>>4)*4 + rr
#pragma unroll
    for (int rr = 0; rr < 4; ++rr)
#pragma unroll
        for (int n = 0; n < 8; ++n)
            WA[w * 16 + q * 4 + rr][n * 16 + r16] = f2bf(acc[n][rr]);

    __syncthreads();   // A-tile ready

    // ---- edge phase: quarter-wave per edge, 4 in flight ----
    const int cnt = min(cnt_arr[bkt], BKT_CAP);
    const int2* eb = ed + (size_t)bkt * BKT_CAP;
    for (int p = qw; p < cnt; p += 128) {
        int2 pe[4];
        bool has[4];
#pragma unroll
        for (int u = 0; u < 4; ++u) {
            int pp = p + u * 32;
            has[u] = pp < cnt;
            pe[u] = has[u] ? eb[pp] : eb[p];
        }
        bf16x8 bv[4], av[4];
#pragma unroll
        for (int u = 0; u < 4; ++u) {
            bv[u] = *(const bf16x8*)(B + (size_t)pe[u].x * NFEATS + r16 * 8);
            av[u] = *(const bf16x8*)&WA[(pe[u].y >> 20) & 127][r16 * 8];
        }
        float s[4];
#pragma unroll
        for (int u = 0; u < 4; ++u) {
            float sc = 0.f;
#pragma unroll
            for (int j = 0; j < 8; ++j) {
                float h = bf2f(av[u][j]) + bf2f(bv[u][j]);
                h = fmaxf(h, 0.f);
                sc = fmaf(h, w2v[j], sc);
            }
            s[u] = sc;
        }
#pragma unroll
        for (int sh = 1; sh <= 8; sh <<= 1)
#pragma unroll
            for (int u = 0; u < 4; ++u)
                s[u] += __shfl_xor(s[u], sh);
        if (r16 == 0) {
#pragma unroll
            for (int u = 0; u < 4; ++u)
                if (has[u]) out[pe[u].y & 0xFFFFF] = s[u] + b2v;
        }
    }
}

extern "C" void kernel_launch(void* const* d_in, const int* in_sizes, int n_in,
                              void* d_out, int out_size, void* d_ws, size_t ws_size,
                              hipStream_t stream) {
    const float* item = (const float*)d_in[0];
    const float* user = (const float*)d_in[1];
    const float* W1   = (const float*)d_in[2];
    const float* b1   = (const float*)d_in[3];
    const float* W2   = (const float*)d_in[4];
    const float* b2   = (const float*)d_in[5];
    const int*   src  = (const int*)d_in[6];
    const int*   dst  = (const int*)d_in[7];
    float* out = (float*)d_out;

    const int n_nodes = in_sizes[0] / NFEATS;
    const int n_edges = in_sizes[6];
    const int nbkt = (n_nodes + 127) >> 7;

    // workspace layout
    short* B = (short*)d_ws;                                  // [n_nodes][128] bf16
    size_t off = (size_t)n_nodes * NFEATS * 2;
    off = (off + 255) & ~(size_t)255;
    int* cur = (int*)((uint8_t*)d_ws + off);                  // [nbkt]
    off += ((size_t)nbkt * 4 + 255) & ~(size_t)255;
    int2* ed = (int2*)((uint8_t*)d_ws + off);                 // [nbkt][BKT_CAP]

    zero_kernel<<<1, 1024, 0, stream>>>(cur, nbkt);
    scatter_kernel<<<64, 1024, 0, stream>>>(src, dst, cur, ed, n_edges, nbkt);
    precompute_B_kernel<<<512, 512, 0, stream>>>(user, W1, B, n_nodes);
    fused_kernel<<<nbkt, 512, 0, stream>>>(
        item, W1, b1, W2, b2, B, ed, cur, out, n_nodes, nbkt);
}

// Round 12
// 80.687 us; speedup vs baseline: 2.7752x; 1.0748x over previous
//
#include <hip/hip_runtime.h>
#include <hip/hip_bf16.h>
#include <stdint.h>

#define NFEATS 128

typedef __attribute__((ext_vector_type(8))) short bf16x8;
typedef __attribute__((ext_vector_type(4))) float f32x4;
typedef __attribute__((ext_vector_type(4))) short short4v;

__device__ inline short f2bf(float f) {
    union { float f; unsigned u; } c; c.f = f;
    unsigned u = c.u;
    return (short)((u + 0x7FFFu + ((u >> 16) & 1u)) >> 16);  // RNE
}
__device__ inline float bf2f(short v) {
    union { unsigned u; float f; } c;
    c.u = ((unsigned)(unsigned short)v) << 16;
    return c.f;
}

// Fused precompute for both tables (blockIdx.y selects):
//   y == 0: A[n,j] = sum_k item[n,k] * W1[j,   k] + b1[j]
//   y == 1: B[n,j] = sum_k user[n,k] * W1[j,128+k]
// Canonical staging: W -> LDS once -> W frags lifted to registers; X tiles
// (64 rows x 128 f32 = 32 KB) staged via global_load_lds (linear LDS dest,
// XOR-swizzled GLOBAL source so swizzled ds_read_b128 frags are conflict-lite),
// double-buffered (buf0 recycles the W region). 8 waves: wave = (rowgrp 0..3,
// colhalf 0..1) -> 16 rows x 64 cols per wave, 16 MFMA per tile.
// Best measured configuration (R5): 80.5 us total.
__global__ __launch_bounds__(512, 4) void precompute_kernel(
    const float* __restrict__ item, const float* __restrict__ user,
    const float* __restrict__ W1, const float* __restrict__ b1,
    short* __restrict__ A, short* __restrict__ B, int n_nodes)
{
    __shared__ __align__(1024) uint8_t lds[34816 + 32768];  // [W/buf0 | buf1]

    const int which = blockIdx.y;
    const float* __restrict__ X = which ? user : item;
    short* __restrict__ Out = which ? B : A;
    const int k_off4 = which ? 32 : 0;   // in float4 units (128 floats)

    const int tid = threadIdx.x;
    const int w = tid >> 6, lane = tid & 63;
    const int r16 = lane & 15, q = lane >> 4;     // q in 0..3
    const int rowgrp = w >> 1, colhalf = w & 1;

    // ---- stage W (fp32 -> bf16) into padded LDS ----
    {
        short (*Wl)[136] = (short (*)[136])lds;
        const float4* W4 = (const float4*)W1;     // row stride 64 float4
        for (int i = tid; i < 128 * 32; i += 512) {
            int j = i >> 5, c = i & 31;
            float4 wv = W4[j * 64 + k_off4 + c];
            short4v p;
            p[0] = f2bf(wv.x); p[1] = f2bf(wv.y); p[2] = f2bf(wv.z); p[3] = f2bf(wv.w);
            *(short4v*)&Wl[j][c * 4] = p;
        }
    }
    __syncthreads();

    // ---- lift this wave's W fragments + bias into registers ----
    bf16x8 wfrag[4][4];
    float bias[4];
    {
        short (*Wl)[136] = (short (*)[136])lds;
#pragma unroll
        for (int n = 0; n < 4; ++n) {
            int col = colhalf * 64 + n * 16 + r16;
#pragma unroll
            for (int kk = 0; kk < 4; ++kk)
                wfrag[n][kk] = *(const bf16x8*)&Wl[col][kk * 32 + q * 8];
            bias[n] = which ? 0.f : b1[col];
        }
    }
    __syncthreads();   // W region now reusable as X buffer 0

    const int n_tiles = (n_nodes + 63) >> 6;

    // Stage one 64-row tile into buffer `buf` (linear LDS, swizzled global src).
    // Storage rule: X[row r][16B-chunk c] lives at LDS r*512 + (c^(r&7))*16.
    auto stage = [&](int buf, int t) {
        uint8_t* base = lds + buf * 34816;
#pragma unroll
        for (int i = 0; i < 4; ++i) {
            int o = (w << 12) + (i << 10) + (lane << 4);   // linear byte off in tile
            int r = o >> 9;
            int c_lds = (o >> 4) & 31;
            int node = (t << 6) + r;
            if (node >= n_nodes) node = n_nodes - 1;       // clamp (stores predicated)
            const uint8_t* gp = (const uint8_t*)X + (size_t)node * 512
                              + (size_t)(((c_lds ^ (r & 7)) << 4));
            auto g1 = (const __attribute__((address_space(1))) uint32_t*)gp;
            auto l3 = (__attribute__((address_space(3))) uint32_t*)(base + (w << 12) + (i << 10));
            __builtin_amdgcn_global_load_lds(g1, l3, 16, 0, 0);
        }
    };

    int t = blockIdx.x;
    if (t < n_tiles) stage(0, t);
    int cur = 0;

    for (; t < n_tiles; t += gridDim.x) {
        __syncthreads();                         // drains vmcnt -> buf[cur] ready
        int tn = t + gridDim.x;
        if (tn < n_tiles) stage(cur ^ 1, tn);    // async prefetch next tile

        // ---- fragments from buf[cur] (swizzled ds_read_b128) ----
        const uint8_t* base = lds + cur * 34816;
        const int r = rowgrp * 16 + r16;
        const uint8_t* rowp = base + r * 512;
        const int s = r & 7;
        bf16x8 afrag[4];
#pragma unroll
        for (int kk = 0; kk < 4; ++kk) {
            int c0 = kk * 8 + q * 2;
            float4 v0 = *(const float4*)(rowp + ((c0 ^ s) << 4));
            float4 v1 = *(const float4*)(rowp + (((c0 + 1) ^ s) << 4));
            bf16x8 f;
            f[0] = f2bf(v0.x); f[1] = f2bf(v0.y); f[2] = f2bf(v0.z); f[3] = f2bf(v0.w);
            f[4] = f2bf(v1.x); f[5] = f2bf(v1.y); f[6] = f2bf(v1.z); f[7] = f2bf(v1.w);
            afrag[kk] = f;
        }

        f32x4 acc[4];
#pragma unroll
        for (int n = 0; n < 4; ++n) {
            f32x4 init = {bias[n], bias[n], bias[n], bias[n]};
            acc[n] = init;
        }
#pragma unroll
        for (int n = 0; n < 4; ++n)
#pragma unroll
            for (int kk = 0; kk < 4; ++kk)
                acc[n] = __builtin_amdgcn_mfma_f32_16x16x32_bf16(afrag[kk], wfrag[n][kk], acc[n], 0, 0, 0);

        // C/D layout: col = lane&15, row = (lane>>4)*4 + rr
        const int row0 = (t << 6) + rowgrp * 16 + q * 4;
#pragma unroll
        for (int rr = 0; rr < 4; ++rr) {
            int row = row0 + rr;
            if (row < n_nodes) {
                short* orow = Out + (size_t)row * NFEATS;
#pragma unroll
                for (int n = 0; n < 4; ++n)
                    orow[colhalf * 64 + n * 16 + r16] = f2bf(acc[n][rr]);
            }
        }
        cur ^= 1;
    }
}

// Edge stage: score[e] = dot(relu(A[src[e]] + B[dst[e]]), w2) + b2
// One quarter-wave (16 lanes) per edge, 2 edges in flight per iteration.
// At the random-gather L2-miss service ceiling (~3.2 TB/s): 146 MB fabric
// traffic in 45.8 us; deeper ILP measured null (R2).
__global__ __launch_bounds__(256) void edge_kernel(
    const short* __restrict__ A, const short* __restrict__ B,
    const int* __restrict__ src, const int* __restrict__ dst,
    const float* __restrict__ W2, const float* __restrict__ b2,
    float* __restrict__ out, int n_edges)
{
    const int t = blockIdx.x * 256 + threadIdx.x;
    const int lane16 = threadIdx.x & 15;

    float w2v[8];
#pragma unroll
    for (int j = 0; j < 8; ++j) w2v[j] = W2[lane16 * 8 + j];
    const float b2v = b2[0];

    const int qw = t >> 4;
    const int nqw = (gridDim.x * 256) >> 4;

    for (int e0 = qw; e0 < n_edges; e0 += 2 * nqw) {
        const int e1 = e0 + nqw;
        const bool has1 = e1 < n_edges;

        int s0 = src[e0], d0 = dst[e0];
        int s1 = has1 ? src[e1] : s0;
        int d1 = has1 ? dst[e1] : d0;

        bf16x8 av0 = *(const bf16x8*)(A + (size_t)s0 * NFEATS + lane16 * 8);
        bf16x8 bv0 = *(const bf16x8*)(B + (size_t)d0 * NFEATS + lane16 * 8);
        bf16x8 av1 = *(const bf16x8*)(A + (size_t)s1 * NFEATS + lane16 * 8);
        bf16x8 bv1 = *(const bf16x8*)(B + (size_t)d1 * NFEATS + lane16 * 8);

        float acc0 = 0.f, acc1 = 0.f;
#pragma unroll
        for (int j = 0; j < 8; ++j) {
            float h0 = bf2f(av0[j]) + bf2f(bv0[j]);
            h0 = fmaxf(h0, 0.f);
            acc0 = fmaf(h0, w2v[j], acc0);
            float h1 = bf2f(av1[j]) + bf2f(bv1[j]);
            h1 = fmaxf(h1, 0.f);
            acc1 = fmaf(h1, w2v[j], acc1);
        }
#pragma unroll
        for (int sh = 1; sh <= 8; sh <<= 1) {
            acc0 += __shfl_xor(acc0, sh);
            acc1 += __shfl_xor(acc1, sh);
        }
        if (lane16 == 0) {
            out[e0] = acc0 + b2v;
            if (has1) out[e1] = acc1 + b2v;
        }
    }
}

extern "C" void kernel_launch(void* const* d_in, const int* in_sizes, int n_in,
                              void* d_out, int out_size, void* d_ws, size_t ws_size,
                              hipStream_t stream) {
    const float* item = (const float*)d_in[0];
    const float* user = (const float*)d_in[1];
    const float* W1   = (const float*)d_in[2];
    const float* b1   = (const float*)d_in[3];
    const float* W2   = (const float*)d_in[4];
    const float* b2   = (const float*)d_in[5];
    const int*   src  = (const int*)d_in[6];
    const int*   dst  = (const int*)d_in[7];
    float* out = (float*)d_out;

    const int n_nodes = in_sizes[0] / NFEATS;
    const int n_edges = in_sizes[6];

    short* A = (short*)d_ws;                         // [n_nodes][128] bf16
    short* B = A + (size_t)n_nodes * NFEATS;         // [n_nodes][128] bf16

    dim3 grid(256, 2);                               // 512 blocks = 2/CU resident
    precompute_kernel<<<grid, 512, 0, stream>>>(item, user, W1, b1, A, B, n_nodes);

    edge_kernel<<<2048, 256, 0, stream>>>(A, B, src, dst, W2, b2, out, n_edges);
}